// Round 12
// baseline (368.750 us; speedup 1.0000x reference)
//
#include <hip/hip_runtime.h>
#include <hip/hip_bf16.h>
#include <math.h>

// ---------------- problem constants ----------------
#define NPIX   2500      // 50*50
#define CFEAT  256
#define NTOP   300
#define DFLAT  12544     // 256*7*7
#define FCN    4096
#define FPSTRIDE 3328    // 52 rows * 64 floats per channel (padded feature)
#define KG1    392       // DFLAT/32
#define KG2    128       // FCN/32
#define MT     20        // m-tiles (320 rows padded)

typedef _Float16 f16x8 __attribute__((ext_vector_type(8)));
typedef float    f32x4 __attribute__((ext_vector_type(4)));

// ---------------- workspace offsets (bytes) ----------------
static constexpr size_t OFF_FPAD  = 0;          // 3.4 MB
static constexpr size_t OFF_SCORE = 0x5C0000;
static constexpr size_t OFF_PREB  = 0x5D0000;
static constexpr size_t OFF_KEEP  = 0x5E5000;
static constexpr size_t OFF_IX    = 0x5E6000;
static constexpr size_t OFF_IY    = 0x5EB000;
static constexpr size_t OFF_AFRAG = 0x600000;   // A fragments f16, 8.03 MB
static constexpr size_t OFF_H1F   = 0xE00000;   // h1 fragments f16, 2.62 MB
static constexpr size_t OFF_H2    = 0x1100000;  // h2 f32, 4.9 MB
static constexpr size_t OFF_W1T   = 0x1600000;  // 2.36 MB transient
static constexpr size_t OFF_PART  = 0x1900000;  // cpart (10.2 MB) then split-K partials, time-disjoint

__device__ inline float decode_dim(const void* p) {
    int iv = *(const int*)p;
    if (iv > 0 && iv < (1 << 20)) return (float)iv;
    return __int_as_float(iv);
}

// ---------------- 0. fused: zero padded feature buffer + transpose W1 -------
__global__ void prep_k(float* __restrict__ fpad, const float* __restrict__ W1,
                       float* __restrict__ W1t) {
    int b = blockIdx.x;
    if (b < 832) {
        int i = b * 256 + threadIdx.x;   // float4 index, 212992 total
        if (i < 212992) *(float4*)(fpad + (size_t)i * 4) = make_float4(0.f, 0.f, 0.f, 0.f);
    } else {
        int idx = (b - 832) * 256 + threadIdx.x;
        if (idx < 2304 * 256) {
            int r = idx >> 8, co = idx & 255;
            W1t[idx] = W1[co * 2304 + r];
        }
    }
}

// ---------------- 1. patchify conv -> padded feat -----
// 8 co per block (2x better x reuse); grid (32co, 20p) co-fastest so
// concurrent blocks share the same x tile in L2.
__global__ void __launch_bounds__(128)
patch_conv(const float* __restrict__ x, const float* __restrict__ Wf,
           const float* __restrict__ bf, float* __restrict__ fpad) {
    __shared__ float w[6144];          // 8 co x 768
    int co0 = blockIdx.x * 8;
    for (int t = threadIdx.x; t < 6144; t += 128) w[t] = Wf[co0 * 768 + t];
    __syncthreads();
    int p = blockIdx.y * 128 + threadIdx.x;
    if (p >= NPIX) return;
    int py = p / 50, px = p % 50;
    float acc[8];
    #pragma unroll
    for (int c = 0; c < 8; ++c) acc[c] = bf[co0 + c];
    for (int ci = 0; ci < 3; ++ci) {
        const float* xp = x + ci * 640000 + (py * 16) * 800 + px * 16;
        #pragma unroll
        for (int ky = 0; ky < 16; ++ky) {
            const float* row = xp + ky * 800;
            #pragma unroll
            for (int kq = 0; kq < 4; ++kq) {
                float4 xv = *reinterpret_cast<const float4*>(row + kq * 4);
                int kb = ci * 256 + ky * 16 + kq * 4;
                #pragma unroll
                for (int c = 0; c < 8; ++c) {
                    const float* wc = w + c * 768 + kb;
                    acc[c] += xv.x * wc[0] + xv.y * wc[1] + xv.z * wc[2] + xv.w * wc[3];
                }
            }
        }
    }
    size_t o = (size_t)(py + 1) * 64 + (px + 1);
    #pragma unroll
    for (int c = 0; c < 8; ++c) fpad[(size_t)(co0 + c) * FPSTRIDE + o] = acc[c];
}

// ---------------- 2. 3x3 SAME conv partials (lanes=co, 10-pixel batch, ci/4) --
// grid (5, 50, 4): xgroup of 10, row, ci-chunk of 64. Output: cpart[z][pix][co].
__global__ void __launch_bounds__(256)
conv3x3_part(const float* __restrict__ fpad, const float* __restrict__ W1t,
             float* __restrict__ cpart, int zci) {
    int co = threadIdx.x;
    int xb = blockIdx.x * 10;         // 0,10,20,30,40
    int y  = blockIdx.y;              // 0..49
    int z  = blockIdx.z;
    float acc[10];
    #pragma unroll
    for (int p = 0; p < 10; ++p) acc[p] = 0.0f;
    const float* fp = fpad + (size_t)(z * zci) * FPSTRIDE + (size_t)y * 64 + xb;
    const float* wp = W1t + (size_t)(z * zci) * 9 * 256 + co;
    #pragma unroll 2
    for (int ci = 0; ci < zci; ++ci) {
        float v[3][12];
        #pragma unroll
        for (int dy = 0; dy < 3; ++dy) {
            #pragma unroll
            for (int q = 0; q < 3; ++q) {
                float4 r4 = *(const float4*)(fp + dy * 64 + q * 4);
                v[dy][q * 4 + 0] = r4.x; v[dy][q * 4 + 1] = r4.y;
                v[dy][q * 4 + 2] = r4.z; v[dy][q * 4 + 3] = r4.w;
            }
        }
        float wv[9];
        #pragma unroll
        for (int k = 0; k < 9; ++k) wv[k] = wp[k * 256];
        #pragma unroll
        for (int dy = 0; dy < 3; ++dy)
            #pragma unroll
            for (int dx = 0; dx < 3; ++dx) {
                float wvv = wv[dy * 3 + dx];
                #pragma unroll
                for (int p = 0; p < 10; ++p)
                    acc[p] += v[dy][p + dx] * wvv;
            }
        fp += FPSTRIDE;
        wp += 9 * 256;
    }
    size_t base = (size_t)z * (NPIX * 256) + (size_t)(y * 50 + xb) * 256 + co;
    #pragma unroll
    for (int p = 0; p < 10; ++p)
        cpart[base + (size_t)p * 256] = acc[p];
}

// ---------------- 2b+3. fused: reduce conv partials + bias + relu + heads ---
__global__ void __launch_bounds__(256)
reducehead_k(const float* __restrict__ cpart, const float* __restrict__ b1,
             const float* __restrict__ Wc, const float* __restrict__ bc,
             const float* __restrict__ Wb, const float* __restrict__ bb,
             float* __restrict__ score, float* __restrict__ preb, int zs) {
    int lane = threadIdx.x & 63;
    int p = blockIdx.x * 4 + (threadIdx.x >> 6);
    if (p >= NPIX) return;
    size_t off = (size_t)p * 256 + lane * 4;
    float4 h = *(const float4*)(cpart + off);
    for (int z = 1; z < zs; ++z) {
        float4 v = *(const float4*)(cpart + (size_t)z * (NPIX * 256) + off);
        h.x += v.x; h.y += v.y; h.z += v.z; h.w += v.w;
    }
    float4 b = *(const float4*)(b1 + lane * 4);
    h.x = fmaxf(h.x + b.x, 0.f); h.y = fmaxf(h.y + b.y, 0.f);
    h.z = fmaxf(h.z + b.z, 0.f); h.w = fmaxf(h.w + b.w, 0.f);
    float4 c0 = *(const float4*)(Wc + lane * 4);
    float4 c1 = *(const float4*)(Wc + 256 + lane * 4);
    float4 w0 = *(const float4*)(Wb + lane * 4);
    float4 w1 = *(const float4*)(Wb + 256 + lane * 4);
    float4 w2 = *(const float4*)(Wb + 512 + lane * 4);
    float4 w3 = *(const float4*)(Wb + 768 + lane * 4);
    float s[6];
    s[0] = h.x*c0.x + h.y*c0.y + h.z*c0.z + h.w*c0.w;
    s[1] = h.x*c1.x + h.y*c1.y + h.z*c1.z + h.w*c1.w;
    s[2] = h.x*w0.x + h.y*w0.y + h.z*w0.z + h.w*w0.w;
    s[3] = h.x*w1.x + h.y*w1.y + h.z*w1.z + h.w*w1.w;
    s[4] = h.x*w2.x + h.y*w2.y + h.z*w2.z + h.w*w2.w;
    s[5] = h.x*w3.x + h.y*w3.y + h.z*w3.z + h.w*w3.w;
    #pragma unroll
    for (int o = 1; o < 64; o <<= 1) {
        #pragma unroll
        for (int q = 0; q < 6; ++q) s[q] += __shfl_xor(s[q], o, 64);
    }
    if (lane == 0) {
        float s0 = s[0] + bc[0], s1 = s[1] + bc[1];
        float m = fmaxf(s0, s1);
        float e0 = expf(s0 - m), e1 = expf(s1 - m);
        score[p] = e1 / (e0 + e1);
        preb[p * 4 + 0] = s[2] + bb[0];
        preb[p * 4 + 1] = s[3] + bb[1];
        preb[p * 4 + 2] = s[4] + bb[2];
        preb[p * 4 + 3] = s[5] + bb[3];
    }
}

// ---------------- 4+5+6. fused radix-select top-k + box decode + bitmask NMS --
// 48-bit key = (score_bits << 12) | (~idx & 0xFFF): unique, desc == (score desc, idx asc)
__global__ void __launch_bounds__(1024)
topknms_k(const float* __restrict__ score, const float* __restrict__ preb,
          const void* wp_, const void* hp_, int* __restrict__ keep,
          int* __restrict__ ixb, int* __restrict__ iyb) {
    __shared__ unsigned long long KEYS[NPIX];
    __shared__ unsigned int whist[16][256];     // per-wave histograms
    __shared__ int sh_digit, sh_newr, cnt;
    __shared__ unsigned long long SEL[NTOP];
    __shared__ unsigned long long SORT[NTOP];
    __shared__ float X1[320], Y1[320], X2[320], Y2[320], AR[320];
    __shared__ unsigned long long MASK[320][5];
    __shared__ unsigned long long KEEPW[5];
    int tid = threadIdx.x;
    int lane = tid & 63;
    int w = tid >> 6;

    for (int e = tid; e < NPIX; e += 1024) {
        unsigned sb = __float_as_uint(score[e]);
        KEYS[e] = ((unsigned long long)sb << 12) | (unsigned)((~e) & 0xFFF);
    }
    if (tid == 0) cnt = 0;
    __syncthreads();

    unsigned long long P = 0ull, M = 0ull;
    int r = NTOP;
    for (int pass = 0; pass < 6; ++pass) {
        int shift = 40 - 8 * pass;
        *(uint4*)&whist[w][lane * 4] = uint4{0u, 0u, 0u, 0u};
        for (int e = tid; e < NPIX; e += 1024) {
            unsigned long long k = KEYS[e];
            if ((k & M) == P)
                atomicAdd(&whist[w][(unsigned)(k >> shift) & 255u], 1u);
        }
        __syncthreads();
        if (tid < 64) {
            unsigned c0 = 0, c1 = 0, c2 = 0, c3 = 0;
            #pragma unroll
            for (int ww = 0; ww < 16; ++ww) {
                c0 += whist[ww][tid * 4 + 0];
                c1 += whist[ww][tid * 4 + 1];
                c2 += whist[ww][tid * 4 + 2];
                c3 += whist[ww][tid * 4 + 3];
            }
            unsigned sl = c0 + c1 + c2 + c3;
            unsigned suf = sl;
            #pragma unroll
            for (int off = 1; off < 64; off <<= 1) {
                unsigned o = __shfl_down(suf, off, 64);
                if (lane + off < 64) suf += o;
            }
            unsigned G = suf - sl;
            if (G < (unsigned)r && G + sl >= (unsigned)r) {
                unsigned cc[4] = {c0, c1, c2, c3};
                int d = 0; unsigned ab = G;
                #pragma unroll
                for (int i = 3; i >= 0; --i) {
                    if (ab < (unsigned)r && ab + cc[i] >= (unsigned)r) { d = tid * 4 + i; break; }
                    ab += cc[i];
                }
                sh_digit = d;
                sh_newr = r - (int)ab;
            }
        }
        __syncthreads();
        P |= ((unsigned long long)(unsigned)sh_digit) << shift;
        M |= 0xFFull << shift;
        r = sh_newr;
    }
    unsigned long long T = P;

    for (int e = tid; e < NPIX; e += 1024) {
        unsigned long long k = KEYS[e];
        if (k >= T) {
            int s = atomicAdd(&cnt, 1);
            SEL[s] = k;
        }
    }
    __syncthreads();

    if (tid < NTOP) {
        unsigned long long mine = SEL[tid];
        int rank = 0;
        for (int j = 0; j < NTOP; ++j) rank += (SEL[j] > mine) ? 1 : 0;
        SORT[rank] = mine;
    }
    __syncthreads();

    if (tid < 320) {
        float x1 = 0.f, y1 = 0.f, x2 = 0.f, y2 = 0.f;
        bool v = false;
        if (tid < NTOP) {
            unsigned long long key = SORT[tid];
            int id = 4095 - (int)(key & 0xFFF);
            float sc = __uint_as_float((unsigned)(key >> 12));
            float wf = decode_dim(wp_), hf = decode_dim(hp_);
            float p0 = preb[id * 4 + 0], p1 = preb[id * 4 + 1];
            float p2 = preb[id * 4 + 2], p3 = preb[id * 4 + 3];
            x1 = fmaxf(p2 - p0 * 0.5f, 0.0f);
            y1 = fmaxf(p3 - p1 * 0.5f, 0.0f);
            x2 = fminf(p2 + p0, wf);
            y2 = fminf(p3 + p1, hf);
            v = sc > 0.5f;
            float bx1 = x1 * 0.0625f, by1 = y1 * 0.0625f;
            float bx2 = x2 * 0.0625f, by2 = y2 * 0.0625f;
            #pragma unroll
            for (int m = 0; m < 14; ++m) {
                int i = m >> 1, s = m & 1;
                float frac = ((float)i + (s ? 0.75f : 0.25f)) / 7.0f;
                float xs = bx1 + frac * (bx2 - bx1);
                float ys = by1 + frac * (by2 - by1);
                float fx = floorf(xs); fx = fminf(fmaxf(fx, 0.0f), 49.0f);
                float fy = floorf(ys); fy = fminf(fmaxf(fy, 0.0f), 49.0f);
                ixb[tid * 14 + m] = (int)fx;
                iyb[tid * 14 + m] = (int)fy;
            }
        }
        X1[tid] = x1; Y1[tid] = y1; X2[tid] = x2; Y2[tid] = y2;
        AR[tid] = fmaxf(x2 - x1, 0.0f) * fmaxf(y2 - y1, 0.0f);
        unsigned long long vb = __ballot(v);
        if (lane == 0 && w < 5) KEEPW[w] = vb;
    }
    __syncthreads();

    if (tid < 320) {
        float xi1 = X1[tid], yi1 = Y1[tid], xi2 = X2[tid], yi2 = Y2[tid], ai = AR[tid];
        #pragma unroll
        for (int jw = 0; jw < 5; ++jw) {
            unsigned long long mword = 0ull;
            #pragma unroll 4
            for (int j2 = 0; j2 < 64; ++j2) {
                int j = jw * 64 + j2;
                float ix1 = fmaxf(xi1, X1[j]);
                float iy1 = fmaxf(yi1, Y1[j]);
                float ix2 = fminf(xi2, X2[j]);
                float iy2 = fminf(yi2, Y2[j]);
                float inter = fmaxf(ix2 - ix1, 0.0f) * fmaxf(iy2 - iy1, 0.0f);
                float iou = inter / fmaxf(ai + AR[j] - inter, 1e-6f);
                bool sup = (iou > 0.7f) && (j > tid) && (j < NTOP);
                mword |= sup ? (1ull << j2) : 0ull;
            }
            MASK[tid][jw] = mword;
        }
    }
    __syncthreads();

    if (tid < 64) {
        unsigned long long m[5][5];
        #pragma unroll
        for (int g = 0; g < 5; ++g)
            #pragma unroll
            for (int q = 0; q < 5; ++q)
                m[g][q] = MASK[g * 64 + lane][q];
        unsigned long long kw0 = KEEPW[0], kw1 = KEEPW[1], kw2 = KEEPW[2],
                           kw3 = KEEPW[3], kw4 = KEEPW[4];
        #pragma unroll
        for (int g = 0; g < 5; ++g) {
            for (int i2 = 0; i2 < 64; ++i2) {
                unsigned long long kg = (g == 0) ? kw0 : (g == 1) ? kw1 :
                                        (g == 2) ? kw2 : (g == 3) ? kw3 : kw4;
                bool alive = (kg >> i2) & 1ull;
                unsigned long long b0 = __shfl(m[g][0], i2, 64);
                unsigned long long b1 = __shfl(m[g][1], i2, 64);
                unsigned long long b2 = __shfl(m[g][2], i2, 64);
                unsigned long long b3 = __shfl(m[g][3], i2, 64);
                unsigned long long b4 = __shfl(m[g][4], i2, 64);
                if (alive) {
                    kw0 &= ~b0; kw1 &= ~b1; kw2 &= ~b2; kw3 &= ~b3; kw4 &= ~b4;
                }
            }
        }
        #pragma unroll
        for (int g = 0; g < 5; ++g) {
            unsigned long long kg = (g == 0) ? kw0 : (g == 1) ? kw1 :
                                    (g == 2) ? kw2 : (g == 3) ? kw3 : kw4;
            int j = g * 64 + lane;
            if (j < NTOP) keep[j] = (int)((kg >> lane) & 1ull);
        }
    }
}

// ---------------- 7. ROI max pool -> A fragments (f16, MFMA per-lane layout) -
__global__ void __launch_bounds__(256)
roipool_frag(const float* __restrict__ fpad, const int* __restrict__ ixb,
             const int* __restrict__ iyb, _Float16* __restrict__ Af) {
    int wid = blockIdx.x * 256 + threadIdx.x;
    if (wid >= MT * KG1 * 64) return;
    int l = wid & 63;
    int g = (wid >> 6) % KG1;
    int T = wid / (KG1 * 64);
    int mm = T * 16 + (l & 15);
    int kbase = g * 32 + ((l >> 4) & 3) * 8;
    union { _Float16 h[8]; uint4 u; } o;
    if (mm < NTOP) {
        const int* ix = ixb + mm * 14;
        const int* iy = iyb + mm * 14;
        #pragma unroll
        for (int e = 0; e < 8; ++e) {
            int k = kbase + e;
            int c = k / 49, ij = k % 49, i = ij / 7, jx = ij % 7;
            int y0 = iy[2 * i] + 1, y1 = iy[2 * i + 1] + 1;
            int x0 = ix[2 * jx] + 1, x1 = ix[2 * jx + 1] + 1;
            const float* f = fpad + (size_t)c * FPSTRIDE;
            float v = fmaxf(fmaxf(f[y0 * 64 + x0], f[y0 * 64 + x1]),
                            fmaxf(f[y1 * 64 + x0], f[y1 * 64 + x1]));
            o.h[e] = (_Float16)v;
        }
    } else {
        o.u.x = 0u; o.u.y = 0u; o.u.z = 0u; o.u.w = 0u;
    }
    *(uint4*)(Af + (size_t)wid * 8) = o.u;
}

// ---------------- 8. full-M MFMA GEMM: 512 thr, BN=64, kz-grouped, kk-pipelined
__global__ void __launch_bounds__(512, 4)
gemm_fullm(const _Float16* __restrict__ Af, const float* __restrict__ B,
           float* __restrict__ part, int K, int KG, int kchunk, int ns) {
    __shared__ char Bs[2][64 * 128];   // 64 rows x 64 f16, swizzled
    int tid = threadIdx.x;
    int lane = tid & 63;
    int w = tid >> 6;
    int wm = w & 3, wn = w >> 2;        // 4 m-groups x 2 n-groups
    int wg = blockIdx.x;
    int kz = wg % ns;
    int n0 = (wg / ns) * 64;
    int ks = kz * kchunk;
    int klen = K - ks; if (klen > kchunk) klen = kchunk;
    int nt = klen >> 6;

    f32x4 acc[5][2];
    #pragma unroll
    for (int tm = 0; tm < 5; ++tm)
        #pragma unroll
        for (int tn = 0; tn < 2; ++tn)
            acc[tm][tn] = f32x4{0.f, 0.f, 0.f, 0.f};

    int srow = tid >> 3;          // 0..63
    int skp  = (tid & 7) * 8;     // 0..56
    const float* bsrc = B + (size_t)(n0 + srow) * K + ks + skp;
    int sboff = srow * 128 + ((skp * 2) ^ ((srow & 7) << 4));

    float4 c0a = *(const float4*)(bsrc);
    float4 c0b = *(const float4*)(bsrc + 4);
    float4 c1a, c1b, c2a, c2b;
    if (nt > 1) { c1a = *(const float4*)(bsrc + 64);  c1b = *(const float4*)(bsrc + 68); }
    if (nt > 2) { c2a = *(const float4*)(bsrc + 128); c2b = *(const float4*)(bsrc + 132); }
    {
        union { _Float16 h[8]; uint4 u; } cv;
        cv.h[0] = (_Float16)c0a.x; cv.h[1] = (_Float16)c0a.y;
        cv.h[2] = (_Float16)c0a.z; cv.h[3] = (_Float16)c0a.w;
        cv.h[4] = (_Float16)c0b.x; cv.h[5] = (_Float16)c0b.y;
        cv.h[6] = (_Float16)c0b.z; cv.h[7] = (_Float16)c0b.w;
        *(uint4*)(Bs[0] + sboff) = cv.u;
    }
    __syncthreads();

    for (int k0 = 0; k0 < nt; ++k0) {
        const char* cur = Bs[k0 & 1];
        if (k0 + 1 < nt) {
            union { _Float16 h[8]; uint4 u; } cv;
            cv.h[0] = (_Float16)c1a.x; cv.h[1] = (_Float16)c1a.y;
            cv.h[2] = (_Float16)c1a.z; cv.h[3] = (_Float16)c1a.w;
            cv.h[4] = (_Float16)c1b.x; cv.h[5] = (_Float16)c1b.y;
            cv.h[6] = (_Float16)c1b.z; cv.h[7] = (_Float16)c1b.w;
            *(uint4*)(Bs[(k0 + 1) & 1] + sboff) = cv.u;
        }
        c1a = c2a; c1b = c2b;
        if (k0 + 3 < nt) {
            c2a = *(const float4*)(bsrc + (k0 + 3) * 64);
            c2b = *(const float4*)(bsrc + (k0 + 3) * 64 + 4);
        }
        int g0 = (ks + k0 * 64) >> 5;
        // kk-pipelined fragment loads: prefetch kk=1 frags during kk=0 MFMAs
        f16x8 a_cur[5], b_cur[2], a_nxt[5], b_nxt[2];
        #pragma unroll
        for (int tn = 0; tn < 2; ++tn) {
            int row = wn * 32 + tn * 16 + (lane & 15);
            int kb = (lane >> 4) * 16;
            b_cur[tn] = *(const f16x8*)(cur + row * 128 + (kb ^ ((row & 7) << 4)));
            b_nxt[tn] = *(const f16x8*)(cur + row * 128 + ((kb + 64) ^ ((row & 7) << 4)));
        }
        #pragma unroll
        for (int tm = 0; tm < 5; ++tm) {
            int T = wm * 5 + tm;
            a_cur[tm] = *(const f16x8*)(Af + ((size_t)(T * KG + g0) * 64 + lane) * 8);
            a_nxt[tm] = *(const f16x8*)(Af + ((size_t)(T * KG + g0 + 1) * 64 + lane) * 8);
        }
        #pragma unroll
        for (int tm = 0; tm < 5; ++tm)
            #pragma unroll
            for (int tn = 0; tn < 2; ++tn)
                acc[tm][tn] = __builtin_amdgcn_mfma_f32_16x16x32_f16(a_cur[tm], b_cur[tn], acc[tm][tn], 0, 0, 0);
        #pragma unroll
        for (int tm = 0; tm < 5; ++tm)
            #pragma unroll
            for (int tn = 0; tn < 2; ++tn)
                acc[tm][tn] = __builtin_amdgcn_mfma_f32_16x16x32_f16(a_nxt[tm], b_nxt[tn], acc[tm][tn], 0, 0, 0);
        __syncthreads();
    }
    float* pout = part + (size_t)kz * (NTOP * FCN);
    #pragma unroll
    for (int tm = 0; tm < 5; ++tm) {
        int mbase = (wm * 5 + tm) * 16 + (lane >> 4) * 4;
        #pragma unroll
        for (int j = 0; j < 4; ++j) {
            int m = mbase + j;
            if (m < NTOP) {
                #pragma unroll
                for (int tn = 0; tn < 2; ++tn) {
                    int n = n0 + wn * 32 + tn * 16 + (lane & 15);
                    pout[(size_t)m * FCN + n] = acc[tm][tn][j];
                }
            }
        }
    }
}

// ---------------- 8b. reduce fc1 partials + bias + relu -> h1 fragments f16 --
__global__ void reduce_fc1(const float* __restrict__ part, const float* __restrict__ bias,
                           _Float16* __restrict__ h1f, int ns) {
    int i = blockIdx.x * 256 + threadIdx.x;     // 300*512
    if (i >= NTOP * 512) return;
    int m = i >> 9;
    int f = (i & 511) * 8;
    float s[8];
    const float* p0 = part + (size_t)m * FCN + f;
    #pragma unroll
    for (int e = 0; e < 8; ++e) s[e] = p0[e];
    for (int z = 1; z < ns; ++z) {
        const float* pz = p0 + (size_t)z * (NTOP * FCN);
        #pragma unroll
        for (int e = 0; e < 8; ++e) s[e] += pz[e];
    }
    union { _Float16 h[8]; uint4 u; } o;
    #pragma unroll
    for (int e = 0; e < 8; ++e) o.h[e] = (_Float16)fmaxf(s[e] + bias[f + e], 0.0f);
    int T = m >> 4, g = f >> 5, l = (m & 15) + 16 * ((f >> 3) & 3);
    *(uint4*)(h1f + ((size_t)(T * KG2 + g) * 64 + l) * 8) = o.u;
}

// ---------------- 8c. reduce fc2 partials + bias + relu -> h2 f32 ----------
__global__ void reduce_fc2(const float* __restrict__ part, const float* __restrict__ bias,
                           float* __restrict__ outp, int ns) {
    size_t i = (size_t)blockIdx.x * 256 + threadIdx.x;    // float4 index
    size_t mn4 = (size_t)NTOP * FCN / 4;
    if (i >= mn4) return;
    float4 s = *(const float4*)(part + i * 4);
    for (int zz = 1; zz < ns; ++zz) {
        float4 v = *(const float4*)(part + (size_t)zz * (NTOP * FCN) + i * 4);
        s.x += v.x; s.y += v.y; s.z += v.z; s.w += v.w;
    }
    int n = (int)((i * 4) % FCN);
    float4 b = *(const float4*)(bias + n);
    s.x = fmaxf(s.x + b.x, 0.f); s.y = fmaxf(s.y + b.y, 0.f);
    s.z = fmaxf(s.z + b.z, 0.f); s.w = fmaxf(s.w + b.w, 0.f);
    *(float4*)(outp + i * 4) = s;
}

// ---------------- 9. final heads: wave per output + keep mask ----------------
__global__ void __launch_bounds__(256)
final_k(const float* __restrict__ h2, const float* __restrict__ clsw,
        const float* __restrict__ clsb, const float* __restrict__ boxw,
        const float* __restrict__ boxb, const int* __restrict__ keep,
        float* __restrict__ out) {
    int gid = blockIdx.x * 4 + (threadIdx.x >> 6);
    if (gid >= NTOP * 25) return;
    int lane = threadIdx.x & 63;
    int k = gid / 25, o = gid % 25;
    const float* w;
    float b;
    if (o < 21) { w = clsw + (size_t)o * 4096; b = clsb[o]; }
    else        { w = boxw + (size_t)(o - 21) * 4096; b = boxb[o - 21]; }
    const float* h = h2 + (size_t)k * 4096;
    float s = 0.0f;
    #pragma unroll
    for (int i = 0; i < 16; ++i) {
        float4 hv = *(const float4*)(h + (i * 64 + lane) * 4);
        float4 wv = *(const float4*)(w + (i * 64 + lane) * 4);
        s += hv.x * wv.x + hv.y * wv.y + hv.z * wv.z + hv.w * wv.w;
    }
    #pragma unroll
    for (int off = 1; off < 64; off <<= 1) s += __shfl_xor(s, off, 64);
    if (lane == 0) out[gid] = keep[k] ? (s + b) : 0.0f;
}

// ---------------- launch ----------------
extern "C" void kernel_launch(void* const* d_in, const int* in_sizes, int n_in,
                              void* d_out, int out_size, void* d_ws, size_t ws_size,
                              hipStream_t stream) {
    const float* x    = (const float*)d_in[0];
    const float* Wf   = (const float*)d_in[2];
    const float* bf   = (const float*)d_in[3];
    const float* W1   = (const float*)d_in[4];
    const float* b1   = (const float*)d_in[5];
    const float* Wc   = (const float*)d_in[6];
    const float* bc   = (const float*)d_in[7];
    const float* Wb   = (const float*)d_in[8];
    const float* bb   = (const float*)d_in[9];
    const float* fc1w = (const float*)d_in[10];
    const float* fc1b = (const float*)d_in[11];
    const float* fc2w = (const float*)d_in[12];
    const float* fc2b = (const float*)d_in[13];
    const float* clsw = (const float*)d_in[14];
    const float* clsb = (const float*)d_in[15];
    const float* boxw = (const float*)d_in[16];
    const float* boxb = (const float*)d_in[17];
    const void*  wp   = d_in[18];
    const void*  hp   = d_in[19];

    char* ws = (char*)d_ws;
    float*     fpad  = (float*)(ws + OFF_FPAD);
    float*     score = (float*)(ws + OFF_SCORE);
    float*     preb  = (float*)(ws + OFF_PREB);
    int*       keep  = (int*)(ws + OFF_KEEP);
    int*       ixb   = (int*)(ws + OFF_IX);
    int*       iyb   = (int*)(ws + OFF_IY);
    _Float16*  Af    = (_Float16*)(ws + OFF_AFRAG);
    _Float16*  h1f   = (_Float16*)(ws + OFF_H1F);
    float*     h2    = (float*)(ws + OFF_H2);
    float*     w1t   = (float*)(ws + OFF_W1T);
    float*     out   = (float*)d_out;

    // split-K slots + conv-partial split, guarded by ws_size
    size_t slot = (size_t)NTOP * FCN * 4;   // 4.9 MB
    size_t avail = ws_size > OFF_PART ? (ws_size - OFF_PART) / slot : 0;
    int ns1 = (avail >= 8) ? 8 : (avail >= 4) ? 4 : (avail >= 2) ? 2 : 1;
    int ns2 = ns1;
    float* part1 = (avail >= 1) ? (float*)(ws + OFF_PART) : h2;              // h2 free during fc1
    float* part2 = (avail >= 1) ? (float*)(ws + OFF_PART) : (float*)Af;      // Af free after fc1
    int st1 = (196 + ns1 - 1) / ns1;  int kch1 = st1 * 64;  int ns1e = (196 + st1 - 1) / st1;
    int st2 = (64 + ns2 - 1) / ns2;   int kch2 = st2 * 64;  int ns2e = (64 + st2 - 1) / st2;
    // conv ci-split: 4-way partials (10.2 MB), time-disjoint with fc partials
    int zs = 4;
    float* cpart = (avail >= 3) ? (float*)(ws + OFF_PART) : (float*)(ws + OFF_AFRAG);

    prep_k<<<832 + 2304, 256, 0, stream>>>(fpad, W1, w1t);
    patch_conv<<<dim3(32, 20), 128, 0, stream>>>(x, Wf, bf, fpad);
    conv3x3_part<<<dim3(5, 50, zs), 256, 0, stream>>>(fpad, w1t, cpart, 256 / zs);
    reducehead_k<<<625, 256, 0, stream>>>(cpart, b1, Wc, bc, Wb, bb, score, preb, zs);
    topknms_k<<<1, 1024, 0, stream>>>(score, preb, wp, hp, keep, ixb, iyb);
    roipool_frag<<<(MT * KG1 * 64 + 255) / 256, 256, 0, stream>>>(fpad, ixb, iyb, Af);
    gemm_fullm<<<64 * ns1e, 512, 0, stream>>>(Af, fc1w, part1, DFLAT, KG1, kch1, ns1e);
    reduce_fc1<<<(NTOP * 512 + 255) / 256, 256, 0, stream>>>(part1, fc1b, h1f, ns1e);
    gemm_fullm<<<64 * ns2e, 512, 0, stream>>>(h1f, fc2w, part2, FCN, KG2, kch2, ns2e);
    reduce_fc2<<<(NTOP * FCN / 4 + 255) / 256, 256, 0, stream>>>(part2, fc2b, h2, ns2e);
    final_k<<<(NTOP * 25 + 3) / 4, 256, 0, stream>>>(h2, clsw, clsb, boxw, boxb, keep, out);
}

// Round 13
// 342.621 us; speedup vs baseline: 1.0763x; 1.0763x over previous
//
#include <hip/hip_runtime.h>
#include <hip/hip_bf16.h>
#include <math.h>

// ---------------- problem constants ----------------
#define NPIX   2500      // 50*50
#define CFEAT  256
#define NTOP   300
#define DFLAT  12544     // 256*7*7
#define FCN    4096
#define FPSTRIDE 3328    // 52 rows * 64 floats per channel (padded feature)
#define KG1    392       // DFLAT/32
#define KG2    128       // FCN/32
#define MT     20        // m-tiles (320 rows padded)

typedef _Float16 f16x8 __attribute__((ext_vector_type(8)));
typedef float    f32x4 __attribute__((ext_vector_type(4)));

// ---------------- workspace offsets (bytes) ----------------
static constexpr size_t OFF_FPAD  = 0;          // 3.4 MB
static constexpr size_t OFF_SCORE = 0x5C0000;
static constexpr size_t OFF_PREB  = 0x5D0000;
static constexpr size_t OFF_KEEP  = 0x5E5000;
static constexpr size_t OFF_IX    = 0x5E6000;
static constexpr size_t OFF_IY    = 0x5EB000;
static constexpr size_t OFF_AFRAG = 0x600000;   // A fragments f16, 8.03 MB
static constexpr size_t OFF_H1F   = 0xE00000;   // h1 fragments f16, 2.62 MB
static constexpr size_t OFF_H2    = 0x1100000;  // h2 f32, 4.9 MB
static constexpr size_t OFF_W1T   = 0x1600000;  // 2.36 MB transient
static constexpr size_t OFF_PART  = 0x1900000;  // cpart (20.5 MB) then split-K partials, time-disjoint

__device__ inline float decode_dim(const void* p) {
    int iv = *(const int*)p;
    if (iv > 0 && iv < (1 << 20)) return (float)iv;
    return __int_as_float(iv);
}

// ---------------- 0. fused: zero padded feature buffer + transpose W1 -------
__global__ void prep_k(float* __restrict__ fpad, const float* __restrict__ W1,
                       float* __restrict__ W1t) {
    int b = blockIdx.x;
    if (b < 832) {
        int i = b * 256 + threadIdx.x;   // float4 index, 212992 total
        if (i < 212992) *(float4*)(fpad + (size_t)i * 4) = make_float4(0.f, 0.f, 0.f, 0.f);
    } else {
        int idx = (b - 832) * 256 + threadIdx.x;
        if (idx < 2304 * 256) {
            int r = idx >> 8, co = idx & 255;
            W1t[idx] = W1[co * 2304 + r];
        }
    }
}

// ---------------- 1. patchify conv -> padded feat -----
// grid (64, 10): co-group FASTEST so concurrent blocks share the same x tile (L2).
__global__ void __launch_bounds__(256)
patch_conv(const float* __restrict__ x, const float* __restrict__ Wf,
           const float* __restrict__ bf, float* __restrict__ fpad) {
    __shared__ float w[3072];          // 4 co x 768
    int co0 = blockIdx.x * 4;
    for (int t = threadIdx.x; t < 3072; t += 256) w[t] = Wf[co0 * 768 + t];
    __syncthreads();
    int p = blockIdx.y * 256 + threadIdx.x;
    if (p >= NPIX) return;
    int py = p / 50, px = p % 50;
    float acc[4];
    #pragma unroll
    for (int c = 0; c < 4; ++c) acc[c] = bf[co0 + c];
    for (int ci = 0; ci < 3; ++ci) {
        const float* xp = x + ci * 640000 + (py * 16) * 800 + px * 16;
        #pragma unroll
        for (int ky = 0; ky < 16; ++ky) {
            const float* row = xp + ky * 800;
            #pragma unroll
            for (int kq = 0; kq < 4; ++kq) {
                float4 xv = *reinterpret_cast<const float4*>(row + kq * 4);
                int kb = ci * 256 + ky * 16 + kq * 4;
                #pragma unroll
                for (int c = 0; c < 4; ++c) {
                    const float* wc = w + c * 768 + kb;
                    acc[c] += xv.x * wc[0] + xv.y * wc[1] + xv.z * wc[2] + xv.w * wc[3];
                }
            }
        }
    }
    size_t o = (size_t)(py + 1) * 64 + (px + 1);
    #pragma unroll
    for (int c = 0; c < 4; ++c) fpad[(size_t)(co0 + c) * FPSTRIDE + o] = acc[c];
}

// ---------------- 2. 3x3 SAME conv partials (lanes=co, 8-pixel batch, ci split) --
__global__ void __launch_bounds__(256)
conv3x3_part(const float* __restrict__ fpad, const float* __restrict__ W1t,
             float* __restrict__ cpart, int zci) {
    int co = threadIdx.x;
    int xb = blockIdx.x * 8;          // 0,8,...,48
    int y  = blockIdx.y;              // 0..49
    int z  = blockIdx.z;
    float acc[8];
    #pragma unroll
    for (int p = 0; p < 8; ++p) acc[p] = 0.0f;
    const float* fp = fpad + (size_t)(z * zci) * FPSTRIDE + (size_t)y * 64 + xb;
    const float* wp = W1t + (size_t)(z * zci) * 9 * 256 + co;
    #pragma unroll 2
    for (int ci = 0; ci < zci; ++ci) {
        float v[3][12];
        #pragma unroll
        for (int dy = 0; dy < 3; ++dy) {
            #pragma unroll
            for (int q = 0; q < 3; ++q) {
                float4 r4 = *(const float4*)(fp + dy * 64 + q * 4);
                v[dy][q * 4 + 0] = r4.x; v[dy][q * 4 + 1] = r4.y;
                v[dy][q * 4 + 2] = r4.z; v[dy][q * 4 + 3] = r4.w;
            }
        }
        float wv[9];
        #pragma unroll
        for (int k = 0; k < 9; ++k) wv[k] = wp[k * 256];
        #pragma unroll
        for (int dy = 0; dy < 3; ++dy)
            #pragma unroll
            for (int dx = 0; dx < 3; ++dx) {
                float wvv = wv[dy * 3 + dx];
                #pragma unroll
                for (int p = 0; p < 8; ++p)
                    acc[p] += v[dy][p + dx] * wvv;
            }
        fp += FPSTRIDE;
        wp += 9 * 256;
    }
    size_t base = (size_t)z * (NPIX * 256) + (size_t)(y * 50 + xb) * 256 + co;
    #pragma unroll
    for (int p = 0; p < 8; ++p)
        if (xb + p < 50) cpart[base + (size_t)p * 256] = acc[p];
}

// ---------------- 2b+3. fused: reduce conv partials + bias + relu + heads ---
__global__ void __launch_bounds__(256)
reducehead_k(const float* __restrict__ cpart, const float* __restrict__ b1,
             const float* __restrict__ Wc, const float* __restrict__ bc,
             const float* __restrict__ Wb, const float* __restrict__ bb,
             float* __restrict__ score, float* __restrict__ preb, int zs) {
    int lane = threadIdx.x & 63;
    int p = blockIdx.x * 4 + (threadIdx.x >> 6);
    if (p >= NPIX) return;
    size_t off = (size_t)p * 256 + lane * 4;
    float4 h = *(const float4*)(cpart + off);
    for (int z = 1; z < zs; ++z) {
        float4 v = *(const float4*)(cpart + (size_t)z * (NPIX * 256) + off);
        h.x += v.x; h.y += v.y; h.z += v.z; h.w += v.w;
    }
    float4 b = *(const float4*)(b1 + lane * 4);
    h.x = fmaxf(h.x + b.x, 0.f); h.y = fmaxf(h.y + b.y, 0.f);
    h.z = fmaxf(h.z + b.z, 0.f); h.w = fmaxf(h.w + b.w, 0.f);
    float4 c0 = *(const float4*)(Wc + lane * 4);
    float4 c1 = *(const float4*)(Wc + 256 + lane * 4);
    float4 w0 = *(const float4*)(Wb + lane * 4);
    float4 w1 = *(const float4*)(Wb + 256 + lane * 4);
    float4 w2 = *(const float4*)(Wb + 512 + lane * 4);
    float4 w3 = *(const float4*)(Wb + 768 + lane * 4);
    float s[6];
    s[0] = h.x*c0.x + h.y*c0.y + h.z*c0.z + h.w*c0.w;
    s[1] = h.x*c1.x + h.y*c1.y + h.z*c1.z + h.w*c1.w;
    s[2] = h.x*w0.x + h.y*w0.y + h.z*w0.z + h.w*w0.w;
    s[3] = h.x*w1.x + h.y*w1.y + h.z*w1.z + h.w*w1.w;
    s[4] = h.x*w2.x + h.y*w2.y + h.z*w2.z + h.w*w2.w;
    s[5] = h.x*w3.x + h.y*w3.y + h.z*w3.z + h.w*w3.w;
    #pragma unroll
    for (int o = 1; o < 64; o <<= 1) {
        #pragma unroll
        for (int q = 0; q < 6; ++q) s[q] += __shfl_xor(s[q], o, 64);
    }
    if (lane == 0) {
        float s0 = s[0] + bc[0], s1 = s[1] + bc[1];
        float m = fmaxf(s0, s1);
        float e0 = expf(s0 - m), e1 = expf(s1 - m);
        score[p] = e1 / (e0 + e1);
        preb[p * 4 + 0] = s[2] + bb[0];
        preb[p * 4 + 1] = s[3] + bb[1];
        preb[p * 4 + 2] = s[4] + bb[2];
        preb[p * 4 + 3] = s[5] + bb[3];
    }
}

// ---------------- 4+5+6. fused radix-select top-k + box decode + bitmask NMS --
// 48-bit key = (score_bits << 12) | (~idx & 0xFFF): unique, desc == (score desc, idx asc)
__global__ void __launch_bounds__(1024)
topknms_k(const float* __restrict__ score, const float* __restrict__ preb,
          const void* wp_, const void* hp_, int* __restrict__ keep,
          int* __restrict__ ixb, int* __restrict__ iyb) {
    __shared__ unsigned long long KEYS[NPIX];
    __shared__ unsigned int whist[16][256];     // per-wave histograms
    __shared__ int sh_digit, sh_newr, cnt;
    __shared__ unsigned long long SEL[NTOP];
    __shared__ unsigned long long SORT[NTOP];
    __shared__ float X1[320], Y1[320], X2[320], Y2[320], AR[320];
    __shared__ unsigned long long MASK[320][5];
    __shared__ unsigned long long KEEPW[5];
    int tid = threadIdx.x;
    int lane = tid & 63;
    int w = tid >> 6;

    for (int e = tid; e < NPIX; e += 1024) {
        unsigned sb = __float_as_uint(score[e]);
        KEYS[e] = ((unsigned long long)sb << 12) | (unsigned)((~e) & 0xFFF);
    }
    if (tid == 0) cnt = 0;
    __syncthreads();

    unsigned long long P = 0ull, M = 0ull;
    int r = NTOP;
    for (int pass = 0; pass < 6; ++pass) {
        int shift = 40 - 8 * pass;
        *(uint4*)&whist[w][lane * 4] = uint4{0u, 0u, 0u, 0u};
        for (int e = tid; e < NPIX; e += 1024) {
            unsigned long long k = KEYS[e];
            if ((k & M) == P)
                atomicAdd(&whist[w][(unsigned)(k >> shift) & 255u], 1u);
        }
        __syncthreads();
        if (tid < 64) {
            unsigned c0 = 0, c1 = 0, c2 = 0, c3 = 0;
            #pragma unroll
            for (int ww = 0; ww < 16; ++ww) {
                c0 += whist[ww][tid * 4 + 0];
                c1 += whist[ww][tid * 4 + 1];
                c2 += whist[ww][tid * 4 + 2];
                c3 += whist[ww][tid * 4 + 3];
            }
            unsigned sl = c0 + c1 + c2 + c3;
            unsigned suf = sl;
            #pragma unroll
            for (int off = 1; off < 64; off <<= 1) {
                unsigned o = __shfl_down(suf, off, 64);
                if (lane + off < 64) suf += o;
            }
            unsigned G = suf - sl;
            if (G < (unsigned)r && G + sl >= (unsigned)r) {
                unsigned cc[4] = {c0, c1, c2, c3};
                int d = 0; unsigned ab = G;
                #pragma unroll
                for (int i = 3; i >= 0; --i) {
                    if (ab < (unsigned)r && ab + cc[i] >= (unsigned)r) { d = tid * 4 + i; break; }
                    ab += cc[i];
                }
                sh_digit = d;
                sh_newr = r - (int)ab;
            }
        }
        __syncthreads();
        P |= ((unsigned long long)(unsigned)sh_digit) << shift;
        M |= 0xFFull << shift;
        r = sh_newr;
    }
    unsigned long long T = P;

    for (int e = tid; e < NPIX; e += 1024) {
        unsigned long long k = KEYS[e];
        if (k >= T) {
            int s = atomicAdd(&cnt, 1);
            SEL[s] = k;
        }
    }
    __syncthreads();

    if (tid < NTOP) {
        unsigned long long mine = SEL[tid];
        int rank = 0;
        for (int j = 0; j < NTOP; ++j) rank += (SEL[j] > mine) ? 1 : 0;
        SORT[rank] = mine;
    }
    __syncthreads();

    if (tid < 320) {
        float x1 = 0.f, y1 = 0.f, x2 = 0.f, y2 = 0.f;
        bool v = false;
        if (tid < NTOP) {
            unsigned long long key = SORT[tid];
            int id = 4095 - (int)(key & 0xFFF);
            float sc = __uint_as_float((unsigned)(key >> 12));
            float wf = decode_dim(wp_), hf = decode_dim(hp_);
            float p0 = preb[id * 4 + 0], p1 = preb[id * 4 + 1];
            float p2 = preb[id * 4 + 2], p3 = preb[id * 4 + 3];
            x1 = fmaxf(p2 - p0 * 0.5f, 0.0f);
            y1 = fmaxf(p3 - p1 * 0.5f, 0.0f);
            x2 = fminf(p2 + p0, wf);
            y2 = fminf(p3 + p1, hf);
            v = sc > 0.5f;
            float bx1 = x1 * 0.0625f, by1 = y1 * 0.0625f;
            float bx2 = x2 * 0.0625f, by2 = y2 * 0.0625f;
            #pragma unroll
            for (int m = 0; m < 14; ++m) {
                int i = m >> 1, s = m & 1;
                float frac = ((float)i + (s ? 0.75f : 0.25f)) / 7.0f;
                float xs = bx1 + frac * (bx2 - bx1);
                float ys = by1 + frac * (by2 - by1);
                float fx = floorf(xs); fx = fminf(fmaxf(fx, 0.0f), 49.0f);
                float fy = floorf(ys); fy = fminf(fmaxf(fy, 0.0f), 49.0f);
                ixb[tid * 14 + m] = (int)fx;
                iyb[tid * 14 + m] = (int)fy;
            }
        }
        X1[tid] = x1; Y1[tid] = y1; X2[tid] = x2; Y2[tid] = y2;
        AR[tid] = fmaxf(x2 - x1, 0.0f) * fmaxf(y2 - y1, 0.0f);
        unsigned long long vb = __ballot(v);
        if (lane == 0 && w < 5) KEEPW[w] = vb;
    }
    __syncthreads();

    if (tid < 320) {
        float xi1 = X1[tid], yi1 = Y1[tid], xi2 = X2[tid], yi2 = Y2[tid], ai = AR[tid];
        #pragma unroll
        for (int jw = 0; jw < 5; ++jw) {
            unsigned long long mword = 0ull;
            #pragma unroll 4
            for (int j2 = 0; j2 < 64; ++j2) {
                int j = jw * 64 + j2;
                float ix1 = fmaxf(xi1, X1[j]);
                float iy1 = fmaxf(yi1, Y1[j]);
                float ix2 = fminf(xi2, X2[j]);
                float iy2 = fminf(yi2, Y2[j]);
                float inter = fmaxf(ix2 - ix1, 0.0f) * fmaxf(iy2 - iy1, 0.0f);
                float iou = inter / fmaxf(ai + AR[j] - inter, 1e-6f);
                bool sup = (iou > 0.7f) && (j > tid) && (j < NTOP);
                mword |= sup ? (1ull << j2) : 0ull;
            }
            MASK[tid][jw] = mword;
        }
    }
    __syncthreads();

    if (tid < 64) {
        unsigned long long m[5][5];
        #pragma unroll
        for (int g = 0; g < 5; ++g)
            #pragma unroll
            for (int q = 0; q < 5; ++q)
                m[g][q] = MASK[g * 64 + lane][q];
        unsigned long long kw0 = KEEPW[0], kw1 = KEEPW[1], kw2 = KEEPW[2],
                           kw3 = KEEPW[3], kw4 = KEEPW[4];
        #pragma unroll
        for (int g = 0; g < 5; ++g) {
            for (int i2 = 0; i2 < 64; ++i2) {
                unsigned long long kg = (g == 0) ? kw0 : (g == 1) ? kw1 :
                                        (g == 2) ? kw2 : (g == 3) ? kw3 : kw4;
                bool alive = (kg >> i2) & 1ull;
                unsigned long long b0 = __shfl(m[g][0], i2, 64);
                unsigned long long b1 = __shfl(m[g][1], i2, 64);
                unsigned long long b2 = __shfl(m[g][2], i2, 64);
                unsigned long long b3 = __shfl(m[g][3], i2, 64);
                unsigned long long b4 = __shfl(m[g][4], i2, 64);
                if (alive) {
                    kw0 &= ~b0; kw1 &= ~b1; kw2 &= ~b2; kw3 &= ~b3; kw4 &= ~b4;
                }
            }
        }
        #pragma unroll
        for (int g = 0; g < 5; ++g) {
            unsigned long long kg = (g == 0) ? kw0 : (g == 1) ? kw1 :
                                    (g == 2) ? kw2 : (g == 3) ? kw3 : kw4;
            int j = g * 64 + lane;
            if (j < NTOP) keep[j] = (int)((kg >> lane) & 1ull);
        }
    }
}

// ---------------- 7. ROI max pool -> A fragments (f16, MFMA per-lane layout) -
__global__ void __launch_bounds__(256)
roipool_frag(const float* __restrict__ fpad, const int* __restrict__ ixb,
             const int* __restrict__ iyb, _Float16* __restrict__ Af) {
    int wid = blockIdx.x * 256 + threadIdx.x;
    if (wid >= MT * KG1 * 64) return;
    int l = wid & 63;
    int g = (wid >> 6) % KG1;
    int T = wid / (KG1 * 64);
    int mm = T * 16 + (l & 15);
    int kbase = g * 32 + ((l >> 4) & 3) * 8;
    union { _Float16 h[8]; uint4 u; } o;
    if (mm < NTOP) {
        const int* ix = ixb + mm * 14;
        const int* iy = iyb + mm * 14;
        #pragma unroll
        for (int e = 0; e < 8; ++e) {
            int k = kbase + e;
            int c = k / 49, ij = k % 49, i = ij / 7, jx = ij % 7;
            int y0 = iy[2 * i] + 1, y1 = iy[2 * i + 1] + 1;
            int x0 = ix[2 * jx] + 1, x1 = ix[2 * jx + 1] + 1;
            const float* f = fpad + (size_t)c * FPSTRIDE;
            float v = fmaxf(fmaxf(f[y0 * 64 + x0], f[y0 * 64 + x1]),
                            fmaxf(f[y1 * 64 + x0], f[y1 * 64 + x1]));
            o.h[e] = (_Float16)v;
        }
    } else {
        o.u.x = 0u; o.u.y = 0u; o.u.z = 0u; o.u.w = 0u;
    }
    *(uint4*)(Af + (size_t)wid * 8) = o.u;
}

// ---------------- 8. full-M MFMA GEMM: 512 thr, BN=64, 3-deep B pipeline -----
// 1-D grid of 64*ns blocks: kz = wg % ns (ns=8 aligns kz with XCD round-robin
// -> per-XCD A slice ~1 MB L2-resident). B streamed once, loads 2 iters ahead.
__global__ void __launch_bounds__(512, 4)
gemm_fullm(const _Float16* __restrict__ Af, const float* __restrict__ B,
           float* __restrict__ part, int K, int KG, int kchunk, int ns) {
    __shared__ char Bs[2][64 * 128];   // 64 rows x 64 f16, swizzled
    int tid = threadIdx.x;
    int lane = tid & 63;
    int w = tid >> 6;
    int wm = w & 3, wn = w >> 2;        // 4 m-groups x 2 n-groups
    int wg = blockIdx.x;
    int kz = wg % ns;
    int n0 = (wg / ns) * 64;
    int ks = kz * kchunk;
    int klen = K - ks; if (klen > kchunk) klen = kchunk;
    int nt = klen >> 6;

    f32x4 acc[5][2];
    #pragma unroll
    for (int tm = 0; tm < 5; ++tm)
        #pragma unroll
        for (int tn = 0; tn < 2; ++tn)
            acc[tm][tn] = f32x4{0.f, 0.f, 0.f, 0.f};

    int srow = tid >> 3;          // 0..63
    int skp  = (tid & 7) * 8;     // 0..56
    const float* bsrc = B + (size_t)(n0 + srow) * K + ks + skp;
    int sboff = srow * 128 + ((skp * 2) ^ ((srow & 7) << 4));

    // 3-deep pipeline: c1 = loads for step k0+1, c2 = step k0+2 (rotated)
    float4 c0a = *(const float4*)(bsrc);
    float4 c0b = *(const float4*)(bsrc + 4);
    float4 c1a, c1b, c2a, c2b;
    if (nt > 1) { c1a = *(const float4*)(bsrc + 64);  c1b = *(const float4*)(bsrc + 68); }
    if (nt > 2) { c2a = *(const float4*)(bsrc + 128); c2b = *(const float4*)(bsrc + 132); }
    {
        union { _Float16 h[8]; uint4 u; } cv;
        cv.h[0] = (_Float16)c0a.x; cv.h[1] = (_Float16)c0a.y;
        cv.h[2] = (_Float16)c0a.z; cv.h[3] = (_Float16)c0a.w;
        cv.h[4] = (_Float16)c0b.x; cv.h[5] = (_Float16)c0b.y;
        cv.h[6] = (_Float16)c0b.z; cv.h[7] = (_Float16)c0b.w;
        *(uint4*)(Bs[0] + sboff) = cv.u;
    }
    __syncthreads();

    for (int k0 = 0; k0 < nt; ++k0) {
        const char* cur = Bs[k0 & 1];
        if (k0 + 1 < nt) {
            union { _Float16 h[8]; uint4 u; } cv;
            cv.h[0] = (_Float16)c1a.x; cv.h[1] = (_Float16)c1a.y;
            cv.h[2] = (_Float16)c1a.z; cv.h[3] = (_Float16)c1a.w;
            cv.h[4] = (_Float16)c1b.x; cv.h[5] = (_Float16)c1b.y;
            cv.h[6] = (_Float16)c1b.z; cv.h[7] = (_Float16)c1b.w;
            *(uint4*)(Bs[(k0 + 1) & 1] + sboff) = cv.u;
        }
        // rotate pipeline and issue load for step k0+3 (2 iterations of latency cover)
        c1a = c2a; c1b = c2b;
        if (k0 + 3 < nt) {
            c2a = *(const float4*)(bsrc + (k0 + 3) * 64);
            c2b = *(const float4*)(bsrc + (k0 + 3) * 64 + 4);
        }
        int g0 = (ks + k0 * 64) >> 5;
        #pragma unroll
        for (int kk = 0; kk < 2; ++kk) {
            f16x8 bfr[2];
            #pragma unroll
            for (int tn = 0; tn < 2; ++tn) {
                int row = wn * 32 + tn * 16 + (lane & 15);
                int kb = kk * 64 + (lane >> 4) * 16;
                bfr[tn] = *(const f16x8*)(cur + row * 128 + (kb ^ ((row & 7) << 4)));
            }
            f16x8 a[5];
            #pragma unroll
            for (int tm = 0; tm < 5; ++tm) {
                int T = wm * 5 + tm;
                a[tm] = *(const f16x8*)(Af + ((size_t)(T * KG + g0 + kk) * 64 + lane) * 8);
            }
            #pragma unroll
            for (int tm = 0; tm < 5; ++tm)
                #pragma unroll
                for (int tn = 0; tn < 2; ++tn)
                    acc[tm][tn] = __builtin_amdgcn_mfma_f32_16x16x32_f16(a[tm], bfr[tn], acc[tm][tn], 0, 0, 0);
        }
        __syncthreads();
    }
    float* pout = part + (size_t)kz * (NTOP * FCN);
    #pragma unroll
    for (int tm = 0; tm < 5; ++tm) {
        int mbase = (wm * 5 + tm) * 16 + (lane >> 4) * 4;
        #pragma unroll
        for (int j = 0; j < 4; ++j) {
            int m = mbase + j;
            if (m < NTOP) {
                #pragma unroll
                for (int tn = 0; tn < 2; ++tn) {
                    int n = n0 + wn * 32 + tn * 16 + (lane & 15);
                    pout[(size_t)m * FCN + n] = acc[tm][tn][j];
                }
            }
        }
    }
}

// ---------------- 8b. reduce fc1 partials + bias + relu -> h1 fragments f16 --
__global__ void reduce_fc1(const float* __restrict__ part, const float* __restrict__ bias,
                           _Float16* __restrict__ h1f, int ns) {
    int i = blockIdx.x * 256 + threadIdx.x;     // 300*512
    if (i >= NTOP * 512) return;
    int m = i >> 9;
    int f = (i & 511) * 8;
    float s[8];
    const float* p0 = part + (size_t)m * FCN + f;
    #pragma unroll
    for (int e = 0; e < 8; ++e) s[e] = p0[e];
    for (int z = 1; z < ns; ++z) {
        const float* pz = p0 + (size_t)z * (NTOP * FCN);
        #pragma unroll
        for (int e = 0; e < 8; ++e) s[e] += pz[e];
    }
    union { _Float16 h[8]; uint4 u; } o;
    #pragma unroll
    for (int e = 0; e < 8; ++e) o.h[e] = (_Float16)fmaxf(s[e] + bias[f + e], 0.0f);
    int T = m >> 4, g = f >> 5, l = (m & 15) + 16 * ((f >> 3) & 3);
    *(uint4*)(h1f + ((size_t)(T * KG2 + g) * 64 + l) * 8) = o.u;
}

// ---------------- 8c. reduce fc2 partials + bias + relu -> h2 f32 ----------
__global__ void reduce_fc2(const float* __restrict__ part, const float* __restrict__ bias,
                           float* __restrict__ outp, int ns) {
    size_t i = (size_t)blockIdx.x * 256 + threadIdx.x;    // float4 index
    size_t mn4 = (size_t)NTOP * FCN / 4;
    if (i >= mn4) return;
    float4 s = *(const float4*)(part + i * 4);
    for (int zz = 1; zz < ns; ++zz) {
        float4 v = *(const float4*)(part + (size_t)zz * (NTOP * FCN) + i * 4);
        s.x += v.x; s.y += v.y; s.z += v.z; s.w += v.w;
    }
    int n = (int)((i * 4) % FCN);
    float4 b = *(const float4*)(bias + n);
    s.x = fmaxf(s.x + b.x, 0.f); s.y = fmaxf(s.y + b.y, 0.f);
    s.z = fmaxf(s.z + b.z, 0.f); s.w = fmaxf(s.w + b.w, 0.f);
    *(float4*)(outp + i * 4) = s;
}

// ---------------- 9. final heads: wave per output + keep mask ----------------
__global__ void __launch_bounds__(256)
final_k(const float* __restrict__ h2, const float* __restrict__ clsw,
        const float* __restrict__ clsb, const float* __restrict__ boxw,
        const float* __restrict__ boxb, const int* __restrict__ keep,
        float* __restrict__ out) {
    int gid = blockIdx.x * 4 + (threadIdx.x >> 6);
    if (gid >= NTOP * 25) return;
    int lane = threadIdx.x & 63;
    int k = gid / 25, o = gid % 25;
    const float* w;
    float b;
    if (o < 21) { w = clsw + (size_t)o * 4096; b = clsb[o]; }
    else        { w = boxw + (size_t)(o - 21) * 4096; b = boxb[o - 21]; }
    const float* h = h2 + (size_t)k * 4096;
    float s = 0.0f;
    #pragma unroll
    for (int i = 0; i < 16; ++i) {
        float4 hv = *(const float4*)(h + (i * 64 + lane) * 4);
        float4 wv = *(const float4*)(w + (i * 64 + lane) * 4);
        s += hv.x * wv.x + hv.y * wv.y + hv.z * wv.z + hv.w * wv.w;
    }
    #pragma unroll
    for (int off = 1; off < 64; off <<= 1) s += __shfl_xor(s, off, 64);
    if (lane == 0) out[gid] = keep[k] ? (s + b) : 0.0f;
}

// ---------------- launch ----------------
extern "C" void kernel_launch(void* const* d_in, const int* in_sizes, int n_in,
                              void* d_out, int out_size, void* d_ws, size_t ws_size,
                              hipStream_t stream) {
    const float* x    = (const float*)d_in[0];
    const float* Wf   = (const float*)d_in[2];
    const float* bf   = (const float*)d_in[3];
    const float* W1   = (const float*)d_in[4];
    const float* b1   = (const float*)d_in[5];
    const float* Wc   = (const float*)d_in[6];
    const float* bc   = (const float*)d_in[7];
    const float* Wb   = (const float*)d_in[8];
    const float* bb   = (const float*)d_in[9];
    const float* fc1w = (const float*)d_in[10];
    const float* fc1b = (const float*)d_in[11];
    const float* fc2w = (const float*)d_in[12];
    const float* fc2b = (const float*)d_in[13];
    const float* clsw = (const float*)d_in[14];
    const float* clsb = (const float*)d_in[15];
    const float* boxw = (const float*)d_in[16];
    const float* boxb = (const float*)d_in[17];
    const void*  wp   = d_in[18];
    const void*  hp   = d_in[19];

    char* ws = (char*)d_ws;
    float*     fpad  = (float*)(ws + OFF_FPAD);
    float*     score = (float*)(ws + OFF_SCORE);
    float*     preb  = (float*)(ws + OFF_PREB);
    int*       keep  = (int*)(ws + OFF_KEEP);
    int*       ixb   = (int*)(ws + OFF_IX);
    int*       iyb   = (int*)(ws + OFF_IY);
    _Float16*  Af    = (_Float16*)(ws + OFF_AFRAG);
    _Float16*  h1f   = (_Float16*)(ws + OFF_H1F);
    float*     h2    = (float*)(ws + OFF_H2);
    float*     w1t   = (float*)(ws + OFF_W1T);
    float*     out   = (float*)d_out;

    // split-K slots + conv-partial split, guarded by ws_size
    size_t slot = (size_t)NTOP * FCN * 4;   // 4.9 MB
    size_t avail = ws_size > OFF_PART ? (ws_size - OFF_PART) / slot : 0;
    int ns1 = (avail >= 8) ? 8 : (avail >= 4) ? 4 : (avail >= 2) ? 2 : 1;
    int ns2 = ns1;
    float* part1 = (avail >= 1) ? (float*)(ws + OFF_PART) : h2;              // h2 free during fc1
    float* part2 = (avail >= 1) ? (float*)(ws + OFF_PART) : (float*)Af;      // Af free after fc1
    int st1 = (196 + ns1 - 1) / ns1;  int kch1 = st1 * 64;  int ns1e = (196 + st1 - 1) / st1;
    int st2 = (64 + ns2 - 1) / ns2;   int kch2 = st2 * 64;  int ns2e = (64 + st2 - 1) / st2;
    // conv ci-split: 8-way partials (20.5 MB) share OFF_PART (time-disjoint with fc partials)
    int zs = (avail >= 5) ? 8 : 4;
    float* cpart = (avail >= 5) ? (float*)(ws + OFF_PART) : (float*)(ws + OFF_AFRAG);

    prep_k<<<832 + 2304, 256, 0, stream>>>(fpad, W1, w1t);
    patch_conv<<<dim3(64, 10), 256, 0, stream>>>(x, Wf, bf, fpad);
    conv3x3_part<<<dim3(7, 50, zs), 256, 0, stream>>>(fpad, w1t, cpart, 256 / zs);
    reducehead_k<<<625, 256, 0, stream>>>(cpart, b1, Wc, bc, Wb, bb, score, preb, zs);
    topknms_k<<<1, 1024, 0, stream>>>(score, preb, wp, hp, keep, ixb, iyb);
    roipool_frag<<<(MT * KG1 * 64 + 255) / 256, 256, 0, stream>>>(fpad, ixb, iyb, Af);
    gemm_fullm<<<64 * ns1e, 512, 0, stream>>>(Af, fc1w, part1, DFLAT, KG1, kch1, ns1e);
    reduce_fc1<<<(NTOP * 512 + 255) / 256, 256, 0, stream>>>(part1, fc1b, h1f, ns1e);
    gemm_fullm<<<64 * ns2e, 512, 0, stream>>>(h1f, fc2w, part2, FCN, KG2, kch2, ns2e);
    reduce_fc2<<<(NTOP * FCN / 4 + 255) / 256, 256, 0, stream>>>(part2, fc2b, h2, ns2e);
    final_k<<<(NTOP * 25 + 3) / 4, 256, 0, stream>>>(h2, clsw, clsb, boxw, boxb, keep, out);
}